// Round 8
// baseline (318.313 us; speedup 1.0000x reference)
//
#include <hip/hip_runtime.h>
#include <math.h>

// Problem constants (from reference)
constexpr int Bc   = 256;      // batch
constexpr int KP1  = 4097;     // K negatives + 1
constexpr int Dc   = 128;      // feature dim
constexpr int NROW = 1000000;  // memory bank rows
constexpr float MOM = 0.5f;
constexpr float Tc  = 0.07f;

constexpr int HALF_ROW = NROW / 2;  // 500K rows = 244 MiB, fits 256 MiB L3

// clang-native float4 — __builtin_nontemporal_store rejects HIP_vector_type
typedef float f4 __attribute__((ext_vector_type(4)));

// ---------------------------------------------------------------------------
// Copy a range [lo4, hi4) of the bank (in float4 units). Nontemporal stores
// keep L3 populated with bank READ lines only.
__global__ __launch_bounds__(256) void copy_mem_kernel(const f4* __restrict__ src,
                                                       f4* __restrict__ dst,
                                                       int lo4, int hi4) {
    int i = lo4 + blockIdx.x * 256 + threadIdx.x;
    const int S = gridDim.x * 256;
    for (; i + 3 * S < hi4; i += 4 * S) {
        f4 a0 = src[i];
        f4 a1 = src[i + S];
        f4 a2 = src[i + 2 * S];
        f4 a3 = src[i + 3 * S];
        __builtin_nontemporal_store(a0, &dst[i]);
        __builtin_nontemporal_store(a1, &dst[i + S]);
        __builtin_nontemporal_store(a2, &dst[i + 2 * S]);
        __builtin_nontemporal_store(a3, &dst[i + 3 * S]);
    }
    for (; i < hi4; i += S) __builtin_nontemporal_store(src[i], &dst[i]);
}

// ---------------------------------------------------------------------------
// Momentum scatter-update of rows y[b]; overwrites copied rows.
// Last-write-wins for duplicate y (numpy scatter semantics).
__global__ __launch_bounds__(64) void scatter_kernel(const float* __restrict__ memory,
                                                     const float* __restrict__ ab,
                                                     const int* __restrict__ y,
                                                     float* __restrict__ out_mem) {
    const int b = blockIdx.x;
    const int row = y[b];
    for (int b2 = b + 1; b2 < Bc; ++b2)
        if (y[b2] == row) return;  // a later b writes this row

    const int lane = threadIdx.x;  // 0..63
    float2 m = *(const float2*)(memory + (size_t)row * Dc + lane * 2);
    float2 a = *(const float2*)(ab + b * Dc + lane * 2);
    float v0 = m.x * MOM + a.x * (1.0f - MOM);
    float v1 = m.y * MOM + a.y * (1.0f - MOM);
    float s = v0 * v0 + v1 * v1;
#pragma unroll
    for (int off = 32; off; off >>= 1) s += __shfl_xor(s, off);
    const float inv = 1.0f / sqrtf(s);
    float2 o;
    o.x = v0 * inv;
    o.y = v1 * inv;
    *(float2*)(out_mem + (size_t)row * Dc + lane * 2) = o;
}

// ---------------------------------------------------------------------------
// Gather + 3 fused dot products, HALF-PASS version (r5 structure + row-half
// predicate). pass 0 processes rows < HALF_ROW (L3-hot right after copying
// half 1), pass 1 the rest. Predicate is uniform within each 8-lane group,
// so inactive groups skip their loads entirely.
constexpr int GY    = 32;            // gridDim.y
constexpr int NW    = GY * 4;        // waves per batch row b (128)
constexpr int KSTEP = NW * 8;        // k covered per iteration (1024)
constexpr int NITER = (KP1 + KSTEP - 1) / KSTEP;  // 5

__global__ __launch_bounds__(256) void gather_dot_kernel(
    const float* __restrict__ memory,
    const float* __restrict__ ab,
    const float* __restrict__ l,
    const float* __restrict__ ss,
    const int* __restrict__ idx,
    float* __restrict__ out,
    int pass) {
    const int b    = blockIdx.x;
    const int lane = threadIdx.x & 63;
    const int wid  = (threadIdx.x >> 6) + (blockIdx.y << 2);  // 0..NW-1
    const int g    = lane >> 3;  // k-group 0..7
    const int sub  = lane & 7;   // lane within group

    // preload queries: lane needs float4 at d = it*32 + sub*4
    float4 qa[4], ql[4], qs[4];
#pragma unroll
    for (int it = 0; it < 4; ++it) {
        const int d = it * 32 + sub * 4;
        qa[it] = *(const float4*)(ab + b * Dc + d);
        ql[it] = *(const float4*)(l  + b * Dc + d);
        qs[it] = *(const float4*)(ss + b * Dc + d);
    }
    const int* idxb = idx + (size_t)b * KP1;
    const size_t out_b = (size_t)b * KP1;
    const size_t plane = (size_t)Bc * KP1;
    const float invT = 1.0f / Tc;
    const int kbase = wid * 8 + g;

    // all row indices upfront
    int rows[NITER];
#pragma unroll
    for (int t = 0; t < NITER; ++t) {
        int k = kbase + t * KSTEP;
        rows[t] = idxb[(k < KP1) ? k : (KP1 - 1)];
    }

#pragma unroll
    for (int t = 0; t < NITER; ++t) {
        const int k = kbase + t * KSTEP;
        const bool act = ((rows[t] < HALF_ROW) == (pass == 0)) && (k < KP1);
        if (act) {
            const float* wrow = memory + (size_t)rows[t] * Dc;
            float sa = 0.f, sl = 0.f, s2 = 0.f;
#pragma unroll
            for (int it = 0; it < 4; ++it) {
                const float4 w = *(const float4*)(wrow + it * 32 + sub * 4);
                sa += w.x * qa[it].x + w.y * qa[it].y + w.z * qa[it].z + w.w * qa[it].w;
                sl += w.x * ql[it].x + w.y * ql[it].y + w.z * ql[it].z + w.w * ql[it].w;
                s2 += w.x * qs[it].x + w.y * qs[it].y + w.z * qs[it].z + w.w * qs[it].w;
            }
            // 8-lane group reduce (all 8 lanes of the group are active together)
#pragma unroll
            for (int off = 1; off < 8; off <<= 1) {
                sa += __shfl_xor(sa, off);
                sl += __shfl_xor(sl, off);
                s2 += __shfl_xor(s2, off);
            }
            if (sub == 0) {
                out[0 * plane + out_b + k] = sa * invT;  // out_orig (ab)
                out[1 * plane + out_b + k] = sl * invT;  // out_l
                out[2 * plane + out_b + k] = s2 * invT;  // out_ss
            }
        }
    }
}

// ---------------------------------------------------------------------------
extern "C" void kernel_launch(void* const* d_in, const int* in_sizes, int n_in,
                              void* d_out, int out_size, void* d_ws, size_t ws_size,
                              hipStream_t stream) {
    const float* ab     = (const float*)d_in[0];
    const float* l      = (const float*)d_in[1];
    const float* ss     = (const float*)d_in[2];
    const float* memory = (const float*)d_in[3];
    const int*   idx    = (const int*)d_in[4];
    const int*   y      = (const int*)d_in[5];

    float* out     = (float*)d_out;
    float* out_mem = out + (size_t)3 * Bc * KP1;

    const int n4   = (NROW * Dc) / 4;      // 32M float4
    const int mid4 = (HALF_ROW * Dc) / 4;  // 16M float4 (row 500K boundary)

    // A1: copy half 1 -> L3 holds half-1 bank lines
    copy_mem_kernel<<<dim3(4096), dim3(256), 0, stream>>>(
        (const f4*)memory, (f4*)out_mem, 0, mid4);
    // B1: gather pass 0 (rows < HALF_ROW, L3-hot)
    gather_dot_kernel<<<dim3(Bc, GY), dim3(256), 0, stream>>>(
        memory, ab, l, ss, idx, out, 0);
    // A2: copy half 2
    copy_mem_kernel<<<dim3(4096), dim3(256), 0, stream>>>(
        (const f4*)memory, (f4*)out_mem, mid4, n4);
    // B2: gather pass 1 (rows >= HALF_ROW, L3-hot)
    gather_dot_kernel<<<dim3(Bc, GY), dim3(256), 0, stream>>>(
        memory, ab, l, ss, idx, out, 1);
    // scatter last (overwrites copied y-rows)
    scatter_kernel<<<dim3(Bc), dim3(64), 0, stream>>>(memory, ab, y, out_mem);
}

// Round 9
// 305.448 us; speedup vs baseline: 1.0421x; 1.0421x over previous
//
#include <hip/hip_runtime.h>
#include <math.h>

// Problem constants (from reference)
constexpr int Bc   = 256;      // batch
constexpr int KP1  = 4097;     // K negatives + 1
constexpr int Dc   = 128;      // feature dim
constexpr int NROW = 1000000;  // memory bank rows
constexpr float MOM = 0.5f;
constexpr float Tc  = 0.07f;

// clang-native float4 — __builtin_nontemporal_store rejects HIP_vector_type
typedef float f4 __attribute__((ext_vector_type(4)));

// ---------------------------------------------------------------------------
// Phase A: stream-copy the bank. Nontemporal stores avoid polluting caches
// with write lines. ~1.02 GB of traffic at the streaming ceiling.
__global__ __launch_bounds__(256) void copy_mem_kernel(const f4* __restrict__ src,
                                                       f4* __restrict__ dst,
                                                       int n4) {
    int i = blockIdx.x * 256 + threadIdx.x;
    const int S = gridDim.x * 256;
    for (; i + 3 * S < n4; i += 4 * S) {
        f4 a0 = src[i];
        f4 a1 = src[i + S];
        f4 a2 = src[i + 2 * S];
        f4 a3 = src[i + 3 * S];
        __builtin_nontemporal_store(a0, &dst[i]);
        __builtin_nontemporal_store(a1, &dst[i + S]);
        __builtin_nontemporal_store(a2, &dst[i + 2 * S]);
        __builtin_nontemporal_store(a3, &dst[i + 3 * S]);
    }
    for (; i < n4; i += S) __builtin_nontemporal_store(src[i], &dst[i]);
}

// ---------------------------------------------------------------------------
// Momentum scatter-update of rows y[b]; overwrites copied rows.
// Last-write-wins for duplicate y (numpy scatter semantics).
__global__ __launch_bounds__(64) void scatter_kernel(const float* __restrict__ memory,
                                                     const float* __restrict__ ab,
                                                     const int* __restrict__ y,
                                                     float* __restrict__ out_mem) {
    const int b = blockIdx.x;
    const int row = y[b];
    for (int b2 = b + 1; b2 < Bc; ++b2)
        if (y[b2] == row) return;  // a later b writes this row

    const int lane = threadIdx.x;  // 0..63
    float2 m = *(const float2*)(memory + (size_t)row * Dc + lane * 2);
    float2 a = *(const float2*)(ab + b * Dc + lane * 2);
    float v0 = m.x * MOM + a.x * (1.0f - MOM);
    float v1 = m.y * MOM + a.y * (1.0f - MOM);
    float s = v0 * v0 + v1 * v1;
#pragma unroll
    for (int off = 32; off; off >>= 1) s += __shfl_xor(s, off);
    const float inv = 1.0f / sqrtf(s);
    float2 o;
    o.x = v0 * inv;
    o.y = v1 * inv;
    *(float2*)(out_mem + (size_t)row * Dc + lane * 2) = o;
}

// ---------------------------------------------------------------------------
// Phase B: gather + 3 fused dot products. 8 lanes per (b,k); all row indices
// for this wave's (at most 5) iterations are loaded upfront so row loads of
// iteration t+1 can issue while iteration t reduces (vmcnt vs lgkmcnt are
// independent counters). Queries live in registers for the whole kernel.
constexpr int GY    = 32;            // gridDim.y
constexpr int NW    = GY * 4;        // waves per batch row b (128)
constexpr int KSTEP = NW * 8;        // k covered per iteration (1024)
constexpr int NITER = (KP1 + KSTEP - 1) / KSTEP;  // 5

__global__ __launch_bounds__(256) void gather_dot_kernel(
    const float* __restrict__ memory,
    const float* __restrict__ ab,
    const float* __restrict__ l,
    const float* __restrict__ ss,
    const int* __restrict__ idx,
    float* __restrict__ out) {
    const int b    = blockIdx.x;
    const int lane = threadIdx.x & 63;
    const int wid  = (threadIdx.x >> 6) + (blockIdx.y << 2);  // 0..NW-1
    const int g    = lane >> 3;  // k-group 0..7
    const int sub  = lane & 7;   // lane within group

    // preload queries: lane needs float4 at d = it*32 + sub*4
    float4 qa[4], ql[4], qs[4];
#pragma unroll
    for (int it = 0; it < 4; ++it) {
        const int d = it * 32 + sub * 4;
        qa[it] = *(const float4*)(ab + b * Dc + d);
        ql[it] = *(const float4*)(l  + b * Dc + d);
        qs[it] = *(const float4*)(ss + b * Dc + d);
    }
    const int* idxb = idx + (size_t)b * KP1;
    const size_t out_b = (size_t)b * KP1;
    const size_t plane = (size_t)Bc * KP1;
    const float invT = 1.0f / Tc;
    const int kbase = wid * 8 + g;

    // all row indices upfront (idx loads are L2-hot, latency hidden once)
    int rows[NITER];
#pragma unroll
    for (int t = 0; t < NITER; ++t) {
        int k = kbase + t * KSTEP;
        rows[t] = idxb[(k < KP1) ? k : (KP1 - 1)];
    }

#pragma unroll
    for (int t = 0; t < NITER; ++t) {
        const int k = kbase + t * KSTEP;
        const float* wrow = memory + (size_t)rows[t] * Dc;
        float sa = 0.f, sl = 0.f, s2 = 0.f;
#pragma unroll
        for (int it = 0; it < 4; ++it) {
            const float4 w = *(const float4*)(wrow + it * 32 + sub * 4);
            sa += w.x * qa[it].x + w.y * qa[it].y + w.z * qa[it].z + w.w * qa[it].w;
            sl += w.x * ql[it].x + w.y * ql[it].y + w.z * ql[it].z + w.w * ql[it].w;
            s2 += w.x * qs[it].x + w.y * qs[it].y + w.z * qs[it].z + w.w * qs[it].w;
        }
#pragma unroll
        for (int off = 1; off < 8; off <<= 1) {
            sa += __shfl_xor(sa, off);
            sl += __shfl_xor(sl, off);
            s2 += __shfl_xor(s2, off);
        }
        if (sub == 0 && k < KP1) {
            out[0 * plane + out_b + k] = sa * invT;  // out_orig (ab)
            out[1 * plane + out_b + k] = sl * invT;  // out_l
            out[2 * plane + out_b + k] = s2 * invT;  // out_ss
        }
    }
}

// ---------------------------------------------------------------------------
extern "C" void kernel_launch(void* const* d_in, const int* in_sizes, int n_in,
                              void* d_out, int out_size, void* d_ws, size_t ws_size,
                              hipStream_t stream) {
    const float* ab     = (const float*)d_in[0];
    const float* l      = (const float*)d_in[1];
    const float* ss     = (const float*)d_in[2];
    const float* memory = (const float*)d_in[3];
    const int*   idx    = (const int*)d_in[4];
    const int*   y      = (const int*)d_in[5];

    float* out     = (float*)d_out;
    float* out_mem = out + (size_t)3 * Bc * KP1;

    const int n4 = (NROW * Dc) / 4;  // 32M float4
    copy_mem_kernel<<<dim3(4096), dim3(256), 0, stream>>>(
        (const f4*)memory, (f4*)out_mem, n4);
    scatter_kernel<<<dim3(Bc), dim3(64), 0, stream>>>(memory, ab, y, out_mem);
    gather_dot_kernel<<<dim3(Bc, GY), dim3(256), 0, stream>>>(memory, ab, l, ss, idx, out);
}